// Round 15
// baseline (133.404 us; speedup 1.0000x reference)
//
#include <hip/hip_runtime.h>
#include <hip/hip_bf16.h>

#define BB 4
#define SS 2048
#define DD 768
#define HH 12
#define TD 2304  // 3*D

typedef __bf16 bf16_t;
typedef bf16_t bf16x8 __attribute__((ext_vector_type(8)));
typedef float f32x4 __attribute__((ext_vector_type(4)));
typedef unsigned short u16x4 __attribute__((ext_vector_type(4)));

// async global->LDS, 16B per lane; LDS dest is wave-uniform base (+lane*16 by HW)
__device__ __forceinline__ void gload16(const void* g, void* l) {
  __builtin_amdgcn_global_load_lds((const __attribute__((address_space(1))) void*)g,
                                   (__attribute__((address_space(3))) void*)l, 16, 0, 0);
}

__device__ __forceinline__ unsigned short bf16b(float f) {
  return __builtin_bit_cast(unsigned short, (bf16_t)f);
}

// ---------------- f32 -> bf16 convert (x, w_qkv, w_out) + RoPE trig table ----------------
__global__ __launch_bounds__(256) void k_convert(const float* __restrict__ x,
                                                 const float* __restrict__ wqkv,
                                                 const float* __restrict__ wout,
                                                 unsigned short* __restrict__ xb,
                                                 unsigned short* __restrict__ wqb,
                                                 unsigned short* __restrict__ wob,
                                                 float2* __restrict__ ttab) {
  const int n1 = BB * SS * DD / 4;     // 1572864 float4s
  const int n2 = n1 + TD * DD / 4;     // +442368
  const int n3 = n2 + DD * DD / 4;     // +147456 -> 2162688 = 8448*256
  int i = blockIdx.x * 256 + threadIdx.x;
  if (blockIdx.x >= 8448) {
    int idx = i - 8448 * 256;          // 0..65535 : s = idx>>5, i2 = idx&31
    if (idx < SS * 32) {
      int s = idx >> 5, i2 = idx & 31;
      float inv = __expf(-(float)i2 * (9.210340371976184f / 32.0f));
      float ang = (float)s * inv;
      float sn, cs;
      __sincosf(ang, &sn, &cs);
      ttab[idx] = make_float2(cs, sn);
    }
    return;
  }
  if (i >= n3) return;
  const float4* s;
  unsigned short* d;
  int j;
  if (i < n1)      { s = (const float4*)x;    d = xb;  j = i; }
  else if (i < n2) { s = (const float4*)wqkv; d = wqb; j = i - n1; }
  else             { s = (const float4*)wout; d = wob; j = i - n2; }
  float4 v = s[j];
  u16x4 o;
  o[0] = bf16b(v.x); o[1] = bf16b(v.y); o[2] = bf16b(v.z); o[3] = bf16b(v.w);
  *(u16x4*)(d + (size_t)j * 4) = o;
}

// ---------------- 128x128 bf16 GEMM, C = A * Bw^T ----------------
// BK=64 double-buffered with COUNTED vmcnt (T4): per iter, issue next-tile
// stage (8 gloads), then s_waitcnt vmcnt(8) -- waits only for the PREVIOUS
// tile's loads, leaving the new 8 in flight across the whole iteration.
// EPI==0: QKV epilogue (RoPE from ttab, LDS-staged coalesced stores; v transposed)
// EPI==1: plain f32 store to Cf [M][N]
template <int EPI>
__global__ __launch_bounds__(256) void k_gemm(const unsigned short* __restrict__ A,
                                              const unsigned short* __restrict__ Bw,
                                              float* __restrict__ Cf,
                                              unsigned short* __restrict__ qb,
                                              unsigned short* __restrict__ kb,
                                              unsigned short* __restrict__ vtb,
                                              const float2* __restrict__ ttab,
                                              int K, int N) {
  __shared__ char smem[65536];
  const int tid = threadIdx.x;
  const int lane = tid & 63;
  const int w = tid >> 6, wm = w >> 1, wn = w & 1;
  const int m0 = blockIdx.x * 128, n0 = blockIdx.y * 128;

  const f32x4 zero4 = {0.f, 0.f, 0.f, 0.f};
  f32x4 acc[4][4];
#pragma unroll
  for (int a = 0; a < 4; ++a)
#pragma unroll
    for (int c = 0; c < 4; ++c) acc[a][c] = zero4;

  const int srow = tid >> 3;
  const int sslot = tid & 7;
  const int wbase = (tid & 192) * 16;

  // prologue: stage k-tile 0 into buffer 0 (8 gloads/thread, no wait yet)
#pragma unroll
  for (int i = 0; i < 4; ++i) {
    int row = i * 32 + srow;
    int kg = sslot ^ (row & 7);
    gload16(A + (size_t)(m0 + row) * K + kg * 8, smem + i * 4096 + wbase);
    gload16(Bw + (size_t)(n0 + row) * K + kg * 8, smem + 16384 + i * 4096 + wbase);
  }

  const int nk = K >> 6;  // 12 for K=768
  int cur = 0;
  for (int kt = 0; kt < nk; ++kt) {
    if (kt + 1 < nk) {
      int k0 = (kt + 1) << 6;
#pragma unroll
      for (int i = 0; i < 4; ++i) {
        int row = i * 32 + srow;
        int kg = sslot ^ (row & 7);
        gload16(A + (size_t)(m0 + row) * K + k0 + kg * 8,
                smem + (cur ^ 1) * 32768 + i * 4096 + wbase);
        gload16(Bw + (size_t)(n0 + row) * K + k0 + kg * 8,
                smem + (cur ^ 1) * 32768 + 16384 + i * 4096 + wbase);
      }
      asm volatile("s_waitcnt vmcnt(8)" ::: "memory");  // prev tile arrived; 8 in flight
    } else {
      asm volatile("s_waitcnt vmcnt(0)" ::: "memory");  // last tile: drain
    }
    __builtin_amdgcn_s_barrier();   // all waves' prev-tile data visible

    const char* As = smem + cur * 32768;
    const char* Bs = As + 16384;
#pragma unroll
    for (int kk = 0; kk < 2; ++kk) {
      bf16x8 af[4], bfr[4];
      int colb = (kk * 4 + (lane >> 4)) * 16;
#pragma unroll
      for (int mi = 0; mi < 4; ++mi) {
        int row = wm * 64 + mi * 16 + (lane & 15);
        af[mi] = *(const bf16x8*)(As + row * 128 + (colb ^ ((row & 7) << 4)));
      }
#pragma unroll
      for (int ni = 0; ni < 4; ++ni) {
        int row = wn * 64 + ni * 16 + (lane & 15);
        bfr[ni] = *(const bf16x8*)(Bs + row * 128 + (colb ^ ((row & 7) << 4)));
      }
      __builtin_amdgcn_s_setprio(1);
#pragma unroll
      for (int mi = 0; mi < 4; ++mi)
#pragma unroll
        for (int ni = 0; ni < 4; ++ni)
          acc[mi][ni] = __builtin_amdgcn_mfma_f32_16x16x32_bf16(af[mi], bfr[ni], acc[mi][ni], 0, 0, 0);
      __builtin_amdgcn_s_setprio(0);
    }
    __builtin_amdgcn_s_barrier();   // all waves done reading buf[cur] before re-stage
    cur ^= 1;
  }

  if (EPI == 1) {
#pragma unroll
    for (int mi = 0; mi < 4; ++mi)
#pragma unroll
      for (int ni = 0; ni < 4; ++ni) {
        int ng = n0 + wn * 64 + ni * 16 + (lane & 15);
#pragma unroll
        for (int r = 0; r < 4; ++r) {
          int mg = m0 + wm * 64 + mi * 16 + ((lane >> 4) << 2) + r;
          Cf[(size_t)mg * N + ng] = acc[mi][ni][r];
        }
      }
  } else {
    const float SFT = 0.125f * 1.4426950408889634f;  // 1/sqrt(DH)*log2e folded into Q
    const int part = n0 / DD;          // 0=q 1=k 2=v (block-uniform: 128 | 768)
    const int h0 = (n0 % DD) >> 6;     // first of the 2 heads this block covers
    const int bB = m0 >> 11;           // batch (block-uniform)
    const int s0b = m0 & (SS - 1);     // base sequence position
    char* Cs = smem;                   // 32KB stage (buf0)

    if (part < 2) {
      // ---- q/k: RoPE via table, row-major swizzled stage ----
#pragma unroll
      for (int mi = 0; mi < 4; ++mi) {
#pragma unroll
        for (int r = 0; r < 4; ++r) {
          int lr = wm * 64 + mi * 16 + ((lane >> 4) << 2) + r;
          const float2* tt = ttab + (size_t)(s0b + lr) * 32;
#pragma unroll
          for (int ni = 0; ni < 4; ++ni) {
            int lc = wn * 64 + ni * 16 + (lane & 15);
            int dh = lc & 63;
            float2 cs = tt[dh >> 1];
            float v = acc[mi][ni][r];
            float other = __shfl_xor(v, 1);
            float rr = (dh & 1) ? (other * cs.y + v * cs.x) : (v * cs.x - other * cs.y);
            if (part == 0) rr *= SFT;
            *(unsigned short*)(Cs + lr * 256 + ((lc * 2) ^ ((lr & 7) << 4))) = bf16b(rr);
          }
        }
      }
      __syncthreads();
      unsigned short* dp = (part == 0) ? qb : kb;
      const int j = tid & 15;
      const int head = j >> 3, dh0 = (j & 7) * 8;
#pragma unroll
      for (int t = 0; t < 8; ++t) {
        int lr = t * 16 + (tid >> 4);
        uint4 v16 = *(const uint4*)(Cs + lr * 256 + ((j * 16) ^ ((lr & 7) << 4)));
        *(uint4*)(dp + ((size_t)((bB * HH + h0 + head) * SS) + (s0b + lr)) * 64 + dh0) = v16;
      }
    } else {
      // ---- v: column-major swizzled stage -> transposed coalesced store ----
#pragma unroll
      for (int mi = 0; mi < 4; ++mi) {
#pragma unroll
        for (int r = 0; r < 4; ++r) {
          int lr = wm * 64 + mi * 16 + ((lane >> 4) << 2) + r;
#pragma unroll
          for (int ni = 0; ni < 4; ++ni) {
            int lc = wn * 64 + ni * 16 + (lane & 15);
            *(unsigned short*)(Cs + lc * 256 + ((lr * 2) ^ ((lc & 7) << 4))) =
                bf16b(acc[mi][ni][r]);
          }
        }
      }
      __syncthreads();
      const int j = tid & 15;
#pragma unroll
      for (int t = 0; t < 8; ++t) {
        int vrow = t * 16 + (tid >> 4);      // local col = head*64 + dh
        int head = vrow >> 6, dh = vrow & 63;
        uint4 v16 = *(const uint4*)(Cs + vrow * 256 + ((j * 16) ^ ((vrow & 7) << 4)));
        *(uint4*)(vtb + ((size_t)(bB * HH + h0 + head) * 64 + dh) * SS + s0b + j * 8) = v16;
      }
    }
  }
}

// ---------------- flash attention, causal, BQ=64, 4 waves, paired Q-tiles ----------------
// 1-D grid 768, XCD-grouped decode; counted-vmcnt dbuf K-loop (round-11 skeleton).
// NEW (r15): diagonal kv-tile PEELED out of the main loop -- main loop is
// mask-free and unconditionally stages (branch removed); peeled iteration
// applies the causal mask and handles the pass-transition K0/V0 prefetch.
__global__ __launch_bounds__(256, 4) void k_attn(const unsigned short* __restrict__ qb,
                                                 const unsigned short* __restrict__ kb,
                                                 const unsigned short* __restrict__ vtb,
                                                 unsigned short* __restrict__ ob) {
  __shared__ char smem[40960];
  const int tid = threadIdx.x, lane = tid & 63, w = tid >> 6;
  char* Ps = smem + w * 2048;

  // XCD-grouped decode (bijective): f%8 = XCD slot, group g gets all 16 members there
  const int f = blockIdx.x;                // 0..767
  const int xcd = f & 7, sfl = f >> 3;     // sfl 0..95
  const int g = ((sfl >> 4) << 3) + xcd;   // (b,h) group 0..47
  const int bx = sfl & 15;                 // paired-tile index 0..15
  const int b = g / HH, h = g % HH;
  const size_t bh = (size_t)(b * HH + h);
  const unsigned short* Qg = qb + bh * SS * 64;
  const unsigned short* Kg = kb + bh * SS * 64;
  const unsigned short* Vg = vtb + bh * 64 * SS;

  const int srow = tid >> 3, sslot = tid & 7;
  const int wbase = w * 1024;
  const int qrow_l = lane & 15;
  const int kgrp = lane >> 4;
  const int swz = (qrow_l & 7) << 4;
  const f32x4 kz = {0.f, 0.f, 0.f, 0.f};
  const bf16_t oneb = (bf16_t)1.0f;
  const bf16x8 onev = {oneb, oneb, oneb, oneb, oneb, oneb, oneb, oneb};
  const float THR = 8.0f;

  int qt = 31 - bx;

#pragma unroll
  for (int i = 0; i < 2; ++i) {
    int row = i * 32 + srow;
    int kg = sslot ^ (row & 7);
    gload16(Qg + (size_t)(qt * 64 + row) * 64 + kg * 8, smem + i * 4096 + wbase);
    gload16(Kg + (size_t)row * 64 + kg * 8, smem + 8192 + i * 4096 + wbase);
    gload16(Vg + (size_t)row * SS + kg * 8, smem + 24576 + i * 4096 + wbase);
  }
  __syncthreads();

  int cur = 0;
  for (int pass = 0; pass < 2; ++pass) {
    bf16x8 aq[2];
    {
      int row = w * 16 + qrow_l;
#pragma unroll
      for (int kk = 0; kk < 2; ++kk) {
        int colb = (kk * 4 + kgrp) * 16;
        aq[kk] = *(const bf16x8*)(smem + row * 128 + (colb ^ ((row & 7) << 4)));
      }
    }

    float mI = -1e30f;
    f32x4 accO[4], accL = kz;
#pragma unroll
    for (int nf = 0; nf < 4; ++nf) accO[nf] = kz;
    const int q_glob = qt * 64 + w * 16 + qrow_l;

    // ---- main loop: kvt = 0..qt-1, never diagonal, always stages kvt+1 ----
    for (int kvt = 0; kvt < qt; ++kvt) {
#pragma unroll
      for (int i = 0; i < 2; ++i) {
        int row = i * 32 + srow;
        int kg = sslot ^ (row & 7);
        gload16(Kg + (size_t)((kvt + 1) * 64 + row) * 64 + kg * 8,
                smem + 8192 + (cur ^ 1) * 8192 + i * 4096 + wbase);
        gload16(Vg + (size_t)row * SS + (kvt + 1) * 64 + kg * 8,
                smem + 24576 + (cur ^ 1) * 8192 + i * 4096 + wbase);
      }
      asm volatile("s_waitcnt vmcnt(4)" ::: "memory");  // tile kvt landed; 4 in flight
      __builtin_amdgcn_s_barrier();

      const char* Ks = smem + 8192 + cur * 8192;
      const char* Vs = smem + 24576 + cur * 8192;

      f32x4 accS[4];
      __builtin_amdgcn_s_setprio(1);
#pragma unroll
      for (int nf = 0; nf < 4; ++nf) {
        int row = nf * 16 + qrow_l;
        int rs = (row & 7) << 4;
        bf16x8 bk0 = *(const bf16x8*)(Ks + row * 128 + ((kgrp * 16) ^ rs));
        accS[nf] = __builtin_amdgcn_mfma_f32_16x16x32_bf16(bk0, aq[0], kz, 0, 0, 0);
        bf16x8 bk1 = *(const bf16x8*)(Ks + row * 128 + (((4 + kgrp) * 16) ^ rs));
        accS[nf] = __builtin_amdgcn_mfma_f32_16x16x32_bf16(bk1, aq[1], accS[nf], 0, 0, 0);
      }
      __builtin_amdgcn_s_setprio(0);

      // mask-free per-lane max
      float pmax;
      {
        float a = fmaxf(fmaxf(accS[0][0], accS[0][1]), fmaxf(accS[0][2], accS[0][3]));
        float c = fmaxf(fmaxf(accS[1][0], accS[1][1]), fmaxf(accS[1][2], accS[1][3]));
        float d = fmaxf(fmaxf(accS[2][0], accS[2][1]), fmaxf(accS[2][2], accS[2][3]));
        float e = fmaxf(fmaxf(accS[3][0], accS[3][1]), fmaxf(accS[3][2], accS[3][3]));
        pmax = fmaxf(fmaxf(a, c), fmaxf(d, e));
      }
      if (__any(pmax > mI + THR)) {
        float t = pmax;
        t = fmaxf(t, __shfl_xor(t, 16));
        t = fmaxf(t, __shfl_xor(t, 32));
        float mn = fmaxf(mI, t);
        float al = exp2f(mI - mn);
        mI = mn;
#pragma unroll
        for (int r = 0; r < 4; ++r) {
          float alq = __shfl(al, (kgrp << 2) + r);
          accL[r] *= alq;
#pragma unroll
          for (int nf = 0; nf < 4; ++nf) accO[nf][r] *= alq;
        }
      }

#pragma unroll
      for (int nf = 0; nf < 4; ++nf) {
        float p0 = exp2f(accS[nf][0] - mI);
        float p1 = exp2f(accS[nf][1] - mI);
        float p2 = exp2f(accS[nf][2] - mI);
        float p3 = exp2f(accS[nf][3] - mI);
        uint2 pk;
        pk.x = (unsigned)bf16b(p0) | ((unsigned)bf16b(p1) << 16);
        pk.y = (unsigned)bf16b(p2) | ((unsigned)bf16b(p3) << 16);
        *(uint2*)(Ps + qrow_l * 128 + ((nf * 32 + kgrp * 8) ^ swz)) = pk;
      }

#pragma unroll
      for (int kk = 0; kk < 2; ++kk) {
        int pcol = (kk * 4 + kgrp) * 16;
        bf16x8 pa = *(const bf16x8*)(Ps + qrow_l * 128 + (pcol ^ swz));
        __builtin_amdgcn_s_setprio(1);
#pragma unroll
        for (int nf = 0; nf < 4; ++nf) {
          int vrow = nf * 16 + qrow_l;
          bf16x8 bv = *(const bf16x8*)(Vs + vrow * 128 + (pcol ^ ((vrow & 7) << 4)));
          accO[nf] = __builtin_amdgcn_mfma_f32_16x16x32_bf16(pa, bv, accO[nf], 0, 0, 0);
        }
        accL = __builtin_amdgcn_mfma_f32_16x16x32_bf16(pa, onev, accL, 0, 0, 0);
        __builtin_amdgcn_s_setprio(0);
      }

      __builtin_amdgcn_s_barrier();  // all waves done reading buf[cur]; no vmcnt drain
      cur ^= 1;
    }

    // ---- peeled diagonal iteration: kvt = qt (causal mask applied here) ----
    {
      if (pass == 0) {
        // stage pass-1's K0/V0 into the other buffer
#pragma unroll
        for (int i = 0; i < 2; ++i) {
          int row = i * 32 + srow;
          int kg = sslot ^ (row & 7);
          gload16(Kg + (size_t)row * 64 + kg * 8,
                  smem + 8192 + (cur ^ 1) * 8192 + i * 4096 + wbase);
          gload16(Vg + (size_t)row * SS + kg * 8,
                  smem + 24576 + (cur ^ 1) * 8192 + i * 4096 + wbase);
        }
        asm volatile("s_waitcnt vmcnt(4)" ::: "memory");
      } else {
        asm volatile("s_waitcnt vmcnt(0)" ::: "memory");
      }
      __builtin_amdgcn_s_barrier();

      const char* Ks = smem + 8192 + cur * 8192;
      const char* Vs = smem + 24576 + cur * 8192;

      f32x4 accS[4];
      __builtin_amdgcn_s_setprio(1);
#pragma unroll
      for (int nf = 0; nf < 4; ++nf) {
        int row = nf * 16 + qrow_l;
        int rs = (row & 7) << 4;
        bf16x8 bk0 = *(const bf16x8*)(Ks + row * 128 + ((kgrp * 16) ^ rs));
        accS[nf] = __builtin_amdgcn_mfma_f32_16x16x32_bf16(bk0, aq[0], kz, 0, 0, 0);
        bf16x8 bk1 = *(const bf16x8*)(Ks + row * 128 + (((4 + kgrp) * 16) ^ rs));
        accS[nf] = __builtin_amdgcn_mfma_f32_16x16x32_bf16(bk1, aq[1], accS[nf], 0, 0, 0);
      }
      __builtin_amdgcn_s_setprio(0);

      // causal mask + per-lane max
      float pmax = -1e30f;
#pragma unroll
      for (int nf = 0; nf < 4; ++nf)
#pragma unroll
        for (int r = 0; r < 4; ++r) {
          float s = accS[nf][r];
          if ((qt * 64 + nf * 16 + kgrp * 4 + r) > q_glob) s = -1e30f;
          accS[nf][r] = s;
          pmax = fmaxf(pmax, s);
        }

      if (__any(pmax > mI + THR)) {
        float t = pmax;
        t = fmaxf(t, __shfl_xor(t, 16));
        t = fmaxf(t, __shfl_xor(t, 32));
        float mn = fmaxf(mI, t);
        float al = exp2f(mI - mn);
        mI = mn;
#pragma unroll
        for (int r = 0; r < 4; ++r) {
          float alq = __shfl(al, (kgrp << 2) + r);
          accL[r] *= alq;
#pragma unroll
          for (int nf = 0; nf < 4; ++nf) accO[nf][r] *= alq;
        }
      }

#pragma unroll
      for (int nf = 0; nf < 4; ++nf) {
        float p0 = exp2f(accS[nf][0] - mI);
        float p1 = exp2f(accS[nf][1] - mI);
        float p2 = exp2f(accS[nf][2] - mI);
        float p3 = exp2f(accS[nf][3] - mI);
        uint2 pk;
        pk.x = (unsigned)bf16b(p0) | ((unsigned)bf16b(p1) << 16);
        pk.y = (unsigned)bf16b(p2) | ((unsigned)bf16b(p3) << 16);
        *(uint2*)(Ps + qrow_l * 128 + ((nf * 32 + kgrp * 8) ^ swz)) = pk;
      }

#pragma unroll
      for (int kk = 0; kk < 2; ++kk) {
        int pcol = (kk * 4 + kgrp) * 16;
        bf16x8 pa = *(const bf16x8*)(Ps + qrow_l * 128 + (pcol ^ swz));
        __builtin_amdgcn_s_setprio(1);
#pragma unroll
        for (int nf = 0; nf < 4; ++nf) {
          int vrow = nf * 16 + qrow_l;
          bf16x8 bv = *(const bf16x8*)(Vs + vrow * 128 + (pcol ^ ((vrow & 7) << 4)));
          accO[nf] = __builtin_amdgcn_mfma_f32_16x16x32_bf16(pa, bv, accO[nf], 0, 0, 0);
        }
        accL = __builtin_amdgcn_mfma_f32_16x16x32_bf16(pa, onev, accL, 0, 0, 0);
        __builtin_amdgcn_s_setprio(0);
      }

      __builtin_amdgcn_s_barrier();  // all P/V reads done before Q-restage below
      cur ^= 1;
    }

    if (pass == 0) {
      // stage pass-1's Q (qt=bx) into the Q/P alias region
#pragma unroll
      for (int i = 0; i < 2; ++i) {
        int row = i * 32 + srow;
        int kg = sslot ^ (row & 7);
        gload16(Qg + (size_t)(bx * 64 + row) * 64 + kg * 8, smem + i * 4096 + wbase);
      }
    }

    float inv[4];
#pragma unroll
    for (int r = 0; r < 4; ++r) inv[r] = 1.0f / accL[r];
#pragma unroll
    for (int nf = 0; nf < 4; ++nf) {
      int dh = nf * 16 + qrow_l;
#pragma unroll
      for (int r = 0; r < 4; ++r) {
        int qrow = qt * 64 + w * 16 + (kgrp << 2) + r;
        float o = accO[nf][r] * inv[r];
        ob[((size_t)b * SS + qrow) * DD + h * 64 + dh] = bf16b(o);
      }
    }

    if (pass == 0) {
      qt = bx;
      __syncthreads();  // full drain: Q-stage gloads + K0/V0 settled before pass 1
    }
  }
}

extern "C" void kernel_launch(void* const* d_in, const int* in_sizes, int n_in,
                              void* d_out, int out_size, void* d_ws, size_t ws_size,
                              hipStream_t stream) {
  const float* x = (const float*)d_in[0];
  const float* wqkv = (const float*)d_in[1];
  const float* wout = (const float*)d_in[2];
  float* out = (float*)d_out;
  char* ws = (char*)d_ws;
  unsigned short* xb  = (unsigned short*)(ws);              // [8192][768] bf16
  unsigned short* wqb = (unsigned short*)(ws + 12582912);   // [2304][768]
  unsigned short* wob = (unsigned short*)(ws + 16121856);   // [768][768]
  unsigned short* qb  = (unsigned short*)(ws + 17301504);   // [B][H][S][64]
  unsigned short* kb  = (unsigned short*)(ws + 29884416);   // [B][H][S][64]
  unsigned short* vtb = (unsigned short*)(ws + 42467328);   // [B][H][64][S]
  unsigned short* ob  = (unsigned short*)(ws + 55050240);   // [8192][768]
  // RoPE trig table aliases the ob region (gemm1 reads it BEFORE attn writes ob)
  float2* ttab = (float2*)(ws + 55050240);                  // [2048][32] float2 = 512KB

  k_convert<<<8704, 256, 0, stream>>>(x, wqkv, wout, xb, wqb, wob, ttab);

  dim3 g1(64, 18);  // M/128 x (3D)/128
  k_gemm<0><<<g1, 256, 0, stream>>>(xb, wqb, nullptr, qb, kb, vtb, ttab, 768, 2304);

  k_attn<<<768, 256, 0, stream>>>(qb, kb, vtb, ob);  // XCD-grouped 1-D grid

  dim3 g2(64, 6);  // M/128 x D/128
  k_gemm<1><<<g2, 256, 0, stream>>>(ob, wob, out, nullptr, nullptr, nullptr, nullptr, 768, 768);
}

// Round 16
// 132.057 us; speedup vs baseline: 1.0102x; 1.0102x over previous
//
#include <hip/hip_runtime.h>
#include <hip/hip_bf16.h>

#define BB 4
#define SS 2048
#define DD 768
#define HH 12
#define TD 2304  // 3*D

typedef __bf16 bf16_t;
typedef bf16_t bf16x8 __attribute__((ext_vector_type(8)));
typedef float f32x4 __attribute__((ext_vector_type(4)));
typedef unsigned short u16x4 __attribute__((ext_vector_type(4)));

// async global->LDS, 16B per lane; LDS dest is wave-uniform base (+lane*16 by HW)
__device__ __forceinline__ void gload16(const void* g, void* l) {
  __builtin_amdgcn_global_load_lds((const __attribute__((address_space(1))) void*)g,
                                   (__attribute__((address_space(3))) void*)l, 16, 0, 0);
}

__device__ __forceinline__ unsigned short bf16b(float f) {
  return __builtin_bit_cast(unsigned short, (bf16_t)f);
}

// ---------------- f32 -> bf16 convert (x, w_qkv, w_out) + RoPE trig table ----------------
__global__ __launch_bounds__(256) void k_convert(const float* __restrict__ x,
                                                 const float* __restrict__ wqkv,
                                                 const float* __restrict__ wout,
                                                 unsigned short* __restrict__ xb,
                                                 unsigned short* __restrict__ wqb,
                                                 unsigned short* __restrict__ wob,
                                                 float2* __restrict__ ttab) {
  const int n1 = BB * SS * DD / 4;     // 1572864 float4s
  const int n2 = n1 + TD * DD / 4;     // +442368
  const int n3 = n2 + DD * DD / 4;     // +147456 -> 2162688 = 8448*256
  int i = blockIdx.x * 256 + threadIdx.x;
  if (blockIdx.x >= 8448) {
    int idx = i - 8448 * 256;          // 0..65535 : s = idx>>5, i2 = idx&31
    if (idx < SS * 32) {
      int s = idx >> 5, i2 = idx & 31;
      float inv = __expf(-(float)i2 * (9.210340371976184f / 32.0f));
      float ang = (float)s * inv;
      float sn, cs;
      __sincosf(ang, &sn, &cs);
      ttab[idx] = make_float2(cs, sn);
    }
    return;
  }
  if (i >= n3) return;
  const float4* s;
  unsigned short* d;
  int j;
  if (i < n1)      { s = (const float4*)x;    d = xb;  j = i; }
  else if (i < n2) { s = (const float4*)wqkv; d = wqb; j = i - n1; }
  else             { s = (const float4*)wout; d = wob; j = i - n2; }
  float4 v = s[j];
  u16x4 o;
  o[0] = bf16b(v.x); o[1] = bf16b(v.y); o[2] = bf16b(v.z); o[3] = bf16b(v.w);
  *(u16x4*)(d + (size_t)j * 4) = o;
}

// ---------------- 128x128 bf16 GEMM, C = A * Bw^T ----------------
// BK=64 double-buffered with COUNTED vmcnt (T4): per iter, issue next-tile
// stage (8 gloads), then s_waitcnt vmcnt(8) -- waits only for the PREVIOUS
// tile's loads, leaving the new 8 in flight across the whole iteration.
// EPI==0: QKV epilogue (RoPE from ttab, LDS-staged coalesced stores; v transposed)
// EPI==1: plain f32 store to Cf [M][N]
template <int EPI>
__global__ __launch_bounds__(256) void k_gemm(const unsigned short* __restrict__ A,
                                              const unsigned short* __restrict__ Bw,
                                              float* __restrict__ Cf,
                                              unsigned short* __restrict__ qb,
                                              unsigned short* __restrict__ kb,
                                              unsigned short* __restrict__ vtb,
                                              const float2* __restrict__ ttab,
                                              int K, int N) {
  __shared__ char smem[65536];
  const int tid = threadIdx.x;
  const int lane = tid & 63;
  const int w = tid >> 6, wm = w >> 1, wn = w & 1;
  const int m0 = blockIdx.x * 128, n0 = blockIdx.y * 128;

  const f32x4 zero4 = {0.f, 0.f, 0.f, 0.f};
  f32x4 acc[4][4];
#pragma unroll
  for (int a = 0; a < 4; ++a)
#pragma unroll
    for (int c = 0; c < 4; ++c) acc[a][c] = zero4;

  const int srow = tid >> 3;
  const int sslot = tid & 7;
  const int wbase = (tid & 192) * 16;

  // prologue: stage k-tile 0 into buffer 0 (8 gloads/thread, no wait yet)
#pragma unroll
  for (int i = 0; i < 4; ++i) {
    int row = i * 32 + srow;
    int kg = sslot ^ (row & 7);
    gload16(A + (size_t)(m0 + row) * K + kg * 8, smem + i * 4096 + wbase);
    gload16(Bw + (size_t)(n0 + row) * K + kg * 8, smem + 16384 + i * 4096 + wbase);
  }

  const int nk = K >> 6;  // 12 for K=768
  int cur = 0;
  for (int kt = 0; kt < nk; ++kt) {
    if (kt + 1 < nk) {
      int k0 = (kt + 1) << 6;
#pragma unroll
      for (int i = 0; i < 4; ++i) {
        int row = i * 32 + srow;
        int kg = sslot ^ (row & 7);
        gload16(A + (size_t)(m0 + row) * K + k0 + kg * 8,
                smem + (cur ^ 1) * 32768 + i * 4096 + wbase);
        gload16(Bw + (size_t)(n0 + row) * K + k0 + kg * 8,
                smem + (cur ^ 1) * 32768 + 16384 + i * 4096 + wbase);
      }
      asm volatile("s_waitcnt vmcnt(8)" ::: "memory");  // prev tile arrived; 8 in flight
    } else {
      asm volatile("s_waitcnt vmcnt(0)" ::: "memory");  // last tile: drain
    }
    __builtin_amdgcn_s_barrier();   // all waves' prev-tile data visible

    const char* As = smem + cur * 32768;
    const char* Bs = As + 16384;
#pragma unroll
    for (int kk = 0; kk < 2; ++kk) {
      bf16x8 af[4], bfr[4];
      int colb = (kk * 4 + (lane >> 4)) * 16;
#pragma unroll
      for (int mi = 0; mi < 4; ++mi) {
        int row = wm * 64 + mi * 16 + (lane & 15);
        af[mi] = *(const bf16x8*)(As + row * 128 + (colb ^ ((row & 7) << 4)));
      }
#pragma unroll
      for (int ni = 0; ni < 4; ++ni) {
        int row = wn * 64 + ni * 16 + (lane & 15);
        bfr[ni] = *(const bf16x8*)(Bs + row * 128 + (colb ^ ((row & 7) << 4)));
      }
      __builtin_amdgcn_s_setprio(1);
#pragma unroll
      for (int mi = 0; mi < 4; ++mi)
#pragma unroll
        for (int ni = 0; ni < 4; ++ni)
          acc[mi][ni] = __builtin_amdgcn_mfma_f32_16x16x32_bf16(af[mi], bfr[ni], acc[mi][ni], 0, 0, 0);
      __builtin_amdgcn_s_setprio(0);
    }
    __builtin_amdgcn_s_barrier();   // all waves done reading buf[cur] before re-stage
    cur ^= 1;
  }

  if (EPI == 1) {
#pragma unroll
    for (int mi = 0; mi < 4; ++mi)
#pragma unroll
      for (int ni = 0; ni < 4; ++ni) {
        int ng = n0 + wn * 64 + ni * 16 + (lane & 15);
#pragma unroll
        for (int r = 0; r < 4; ++r) {
          int mg = m0 + wm * 64 + mi * 16 + ((lane >> 4) << 2) + r;
          Cf[(size_t)mg * N + ng] = acc[mi][ni][r];
        }
      }
  } else {
    const float SFT = 0.125f * 1.4426950408889634f;  // 1/sqrt(DH)*log2e folded into Q
    const int part = n0 / DD;          // 0=q 1=k 2=v (block-uniform: 128 | 768)
    const int h0 = (n0 % DD) >> 6;     // first of the 2 heads this block covers
    const int bB = m0 >> 11;           // batch (block-uniform)
    const int s0b = m0 & (SS - 1);     // base sequence position
    char* Cs = smem;                   // 32KB stage (buf0)

    if (part < 2) {
      // ---- q/k: RoPE via table, row-major swizzled stage ----
#pragma unroll
      for (int mi = 0; mi < 4; ++mi) {
#pragma unroll
        for (int r = 0; r < 4; ++r) {
          int lr = wm * 64 + mi * 16 + ((lane >> 4) << 2) + r;
          const float2* tt = ttab + (size_t)(s0b + lr) * 32;
#pragma unroll
          for (int ni = 0; ni < 4; ++ni) {
            int lc = wn * 64 + ni * 16 + (lane & 15);
            int dh = lc & 63;
            float2 cs = tt[dh >> 1];
            float v = acc[mi][ni][r];
            float other = __shfl_xor(v, 1);
            float rr = (dh & 1) ? (other * cs.y + v * cs.x) : (v * cs.x - other * cs.y);
            if (part == 0) rr *= SFT;
            *(unsigned short*)(Cs + lr * 256 + ((lc * 2) ^ ((lr & 7) << 4))) = bf16b(rr);
          }
        }
      }
      __syncthreads();
      unsigned short* dp = (part == 0) ? qb : kb;
      const int j = tid & 15;
      const int head = j >> 3, dh0 = (j & 7) * 8;
#pragma unroll
      for (int t = 0; t < 8; ++t) {
        int lr = t * 16 + (tid >> 4);
        uint4 v16 = *(const uint4*)(Cs + lr * 256 + ((j * 16) ^ ((lr & 7) << 4)));
        *(uint4*)(dp + ((size_t)((bB * HH + h0 + head) * SS) + (s0b + lr)) * 64 + dh0) = v16;
      }
    } else {
      // ---- v: column-major swizzled stage -> transposed coalesced store ----
#pragma unroll
      for (int mi = 0; mi < 4; ++mi) {
#pragma unroll
        for (int r = 0; r < 4; ++r) {
          int lr = wm * 64 + mi * 16 + ((lane >> 4) << 2) + r;
#pragma unroll
          for (int ni = 0; ni < 4; ++ni) {
            int lc = wn * 64 + ni * 16 + (lane & 15);
            *(unsigned short*)(Cs + lc * 256 + ((lr * 2) ^ ((lc & 7) << 4))) =
                bf16b(acc[mi][ni][r]);
          }
        }
      }
      __syncthreads();
      const int j = tid & 15;
#pragma unroll
      for (int t = 0; t < 8; ++t) {
        int vrow = t * 16 + (tid >> 4);      // local col = head*64 + dh
        int head = vrow >> 6, dh = vrow & 63;
        uint4 v16 = *(const uint4*)(Cs + vrow * 256 + ((j * 16) ^ ((vrow & 7) << 4)));
        *(uint4*)(vtb + ((size_t)(bB * HH + h0 + head) * 64 + dh) * SS + s0b + j * 8) = v16;
      }
    }
  }
}

// ---------------- flash attention, causal, BQ=64, 4 waves, paired Q-tiles ----------------
// 1-D grid 768, XCD-grouped decode: all 16 blocks of a (b,h) share blockIdx%8
// -> same XCD L2 caches that (b,h)'s K/V (6 groups x 512KB = 3MB < 4MB L2).
// K-loop uses COUNTED vmcnt (T4): never drains the just-issued prefetch.
__global__ __launch_bounds__(256, 4) void k_attn(const unsigned short* __restrict__ qb,
                                                 const unsigned short* __restrict__ kb,
                                                 const unsigned short* __restrict__ vtb,
                                                 unsigned short* __restrict__ ob) {
  __shared__ char smem[40960];
  const int tid = threadIdx.x, lane = tid & 63, w = tid >> 6;
  char* Ps = smem + w * 2048;

  // XCD-grouped decode (bijective): f%8 = XCD slot, group g gets all 16 members there
  const int f = blockIdx.x;                // 0..767
  const int xcd = f & 7, sfl = f >> 3;     // sfl 0..95
  const int g = ((sfl >> 4) << 3) + xcd;   // (b,h) group 0..47
  const int bx = sfl & 15;                 // paired-tile index 0..15
  const int b = g / HH, h = g % HH;
  const size_t bh = (size_t)(b * HH + h);
  const unsigned short* Qg = qb + bh * SS * 64;
  const unsigned short* Kg = kb + bh * SS * 64;
  const unsigned short* Vg = vtb + bh * 64 * SS;

  const int srow = tid >> 3, sslot = tid & 7;
  const int wbase = w * 1024;
  const int qrow_l = lane & 15;
  const int kgrp = lane >> 4;
  const int swz = (qrow_l & 7) << 4;
  const f32x4 kz = {0.f, 0.f, 0.f, 0.f};
  const bf16_t oneb = (bf16_t)1.0f;
  const bf16x8 onev = {oneb, oneb, oneb, oneb, oneb, oneb, oneb, oneb};
  const float THR = 8.0f;

  int qt = 31 - bx;

#pragma unroll
  for (int i = 0; i < 2; ++i) {
    int row = i * 32 + srow;
    int kg = sslot ^ (row & 7);
    gload16(Qg + (size_t)(qt * 64 + row) * 64 + kg * 8, smem + i * 4096 + wbase);
    gload16(Kg + (size_t)row * 64 + kg * 8, smem + 8192 + i * 4096 + wbase);
    gload16(Vg + (size_t)row * SS + kg * 8, smem + 24576 + i * 4096 + wbase);
  }
  __syncthreads();

  int cur = 0;
  for (int pass = 0; pass < 2; ++pass) {
    bf16x8 aq[2];
    {
      int row = w * 16 + qrow_l;
#pragma unroll
      for (int kk = 0; kk < 2; ++kk) {
        int colb = (kk * 4 + kgrp) * 16;
        aq[kk] = *(const bf16x8*)(smem + row * 128 + (colb ^ ((row & 7) << 4)));
      }
    }

    float mI = -1e30f;
    f32x4 accO[4], accL = kz;
#pragma unroll
    for (int nf = 0; nf < 4; ++nf) accO[nf] = kz;
    const int nkv = qt + 1;
    const int q_glob = qt * 64 + w * 16 + qrow_l;

    for (int kvt = 0; kvt < nkv; ++kvt) {
      // issue next-tile stage (4 gloads), then wait ONLY for the previous
      // tile's 4 loads (counted vmcnt) -- the new 4 stay in flight across
      // the whole compute phase.
      bool staged = true;
      if (kvt + 1 < nkv) {
#pragma unroll
        for (int i = 0; i < 2; ++i) {
          int row = i * 32 + srow;
          int kg = sslot ^ (row & 7);
          gload16(Kg + (size_t)((kvt + 1) * 64 + row) * 64 + kg * 8,
                  smem + 8192 + (cur ^ 1) * 8192 + i * 4096 + wbase);
          gload16(Vg + (size_t)row * SS + (kvt + 1) * 64 + kg * 8,
                  smem + 24576 + (cur ^ 1) * 8192 + i * 4096 + wbase);
        }
      } else if (pass == 0) {
#pragma unroll
        for (int i = 0; i < 2; ++i) {
          int row = i * 32 + srow;
          int kg = sslot ^ (row & 7);
          gload16(Kg + (size_t)row * 64 + kg * 8,
                  smem + 8192 + (cur ^ 1) * 8192 + i * 4096 + wbase);
          gload16(Vg + (size_t)row * SS + kg * 8,
                  smem + 24576 + (cur ^ 1) * 8192 + i * 4096 + wbase);
        }
      } else {
        staged = false;
      }
      if (staged) asm volatile("s_waitcnt vmcnt(4)" ::: "memory");
      else        asm volatile("s_waitcnt vmcnt(0)" ::: "memory");
      __builtin_amdgcn_s_barrier();   // every wave waited its own tile-kvt loads

      const char* Ks = smem + 8192 + cur * 8192;
      const char* Vs = smem + 24576 + cur * 8192;

      f32x4 accS[4];
      __builtin_amdgcn_s_setprio(1);
#pragma unroll
      for (int nf = 0; nf < 4; ++nf) {
        int row = nf * 16 + qrow_l;
        int rs = (row & 7) << 4;
        bf16x8 bk0 = *(const bf16x8*)(Ks + row * 128 + ((kgrp * 16) ^ rs));
        accS[nf] = __builtin_amdgcn_mfma_f32_16x16x32_bf16(bk0, aq[0], kz, 0, 0, 0);
        bf16x8 bk1 = *(const bf16x8*)(Ks + row * 128 + (((4 + kgrp) * 16) ^ rs));
        accS[nf] = __builtin_amdgcn_mfma_f32_16x16x32_bf16(bk1, aq[1], accS[nf], 0, 0, 0);
      }
      __builtin_amdgcn_s_setprio(0);

      const bool diag = (kvt == qt);
      float pmax = -1e30f;
#pragma unroll
      for (int nf = 0; nf < 4; ++nf)
#pragma unroll
        for (int r = 0; r < 4; ++r) {
          float s = accS[nf][r];
          if (diag && (kvt * 64 + nf * 16 + kgrp * 4 + r) > q_glob) s = -1e30f;
          accS[nf][r] = s;
          pmax = fmaxf(pmax, s);
        }

      if (__any(pmax > mI + THR)) {
        float t = pmax;
        t = fmaxf(t, __shfl_xor(t, 16));
        t = fmaxf(t, __shfl_xor(t, 32));
        float mn = fmaxf(mI, t);
        float al = exp2f(mI - mn);
        mI = mn;
#pragma unroll
        for (int r = 0; r < 4; ++r) {
          float alq = __shfl(al, (kgrp << 2) + r);
          accL[r] *= alq;
#pragma unroll
          for (int nf = 0; nf < 4; ++nf) accO[nf][r] *= alq;
        }
      }

#pragma unroll
      for (int nf = 0; nf < 4; ++nf) {
        float p0 = exp2f(accS[nf][0] - mI);
        float p1 = exp2f(accS[nf][1] - mI);
        float p2 = exp2f(accS[nf][2] - mI);
        float p3 = exp2f(accS[nf][3] - mI);
        uint2 pk;
        pk.x = (unsigned)bf16b(p0) | ((unsigned)bf16b(p1) << 16);
        pk.y = (unsigned)bf16b(p2) | ((unsigned)bf16b(p3) << 16);
        *(uint2*)(Ps + qrow_l * 128 + ((nf * 32 + kgrp * 8) ^ swz)) = pk;
      }

#pragma unroll
      for (int kk = 0; kk < 2; ++kk) {
        int pcol = (kk * 4 + kgrp) * 16;
        bf16x8 pa = *(const bf16x8*)(Ps + qrow_l * 128 + (pcol ^ swz));
        __builtin_amdgcn_s_setprio(1);
#pragma unroll
        for (int nf = 0; nf < 4; ++nf) {
          int vrow = nf * 16 + qrow_l;
          bf16x8 bv = *(const bf16x8*)(Vs + vrow * 128 + (pcol ^ ((vrow & 7) << 4)));
          accO[nf] = __builtin_amdgcn_mfma_f32_16x16x32_bf16(pa, bv, accO[nf], 0, 0, 0);
        }
        accL = __builtin_amdgcn_mfma_f32_16x16x32_bf16(pa, onev, accL, 0, 0, 0);
        __builtin_amdgcn_s_setprio(0);
      }

      __builtin_amdgcn_s_barrier();  // all waves done reading buf[cur]; no vmcnt drain
      cur ^= 1;
    }

    if (pass == 0) {
#pragma unroll
      for (int i = 0; i < 2; ++i) {
        int row = i * 32 + srow;
        int kg = sslot ^ (row & 7);
        gload16(Qg + (size_t)(bx * 64 + row) * 64 + kg * 8, smem + i * 4096 + wbase);
      }
    }

    float inv[4];
#pragma unroll
    for (int r = 0; r < 4; ++r) inv[r] = 1.0f / accL[r];
#pragma unroll
    for (int nf = 0; nf < 4; ++nf) {
      int dh = nf * 16 + qrow_l;
#pragma unroll
      for (int r = 0; r < 4; ++r) {
        int qrow = qt * 64 + w * 16 + (kgrp << 2) + r;
        float o = accO[nf][r] * inv[r];
        ob[((size_t)b * SS + qrow) * DD + h * 64 + dh] = bf16b(o);
      }
    }

    if (pass == 0) {
      qt = bx;
      __syncthreads();  // full drain: Q-stage gloads + epilogue stores settled
    }
  }
}

extern "C" void kernel_launch(void* const* d_in, const int* in_sizes, int n_in,
                              void* d_out, int out_size, void* d_ws, size_t ws_size,
                              hipStream_t stream) {
  const float* x = (const float*)d_in[0];
  const float* wqkv = (const float*)d_in[1];
  const float* wout = (const float*)d_in[2];
  float* out = (float*)d_out;
  char* ws = (char*)d_ws;
  unsigned short* xb  = (unsigned short*)(ws);              // [8192][768] bf16
  unsigned short* wqb = (unsigned short*)(ws + 12582912);   // [2304][768]
  unsigned short* wob = (unsigned short*)(ws + 16121856);   // [768][768]
  unsigned short* qb  = (unsigned short*)(ws + 17301504);   // [B][H][S][64]
  unsigned short* kb  = (unsigned short*)(ws + 29884416);   // [B][H][S][64]
  unsigned short* vtb = (unsigned short*)(ws + 42467328);   // [B][H][64][S]
  unsigned short* ob  = (unsigned short*)(ws + 55050240);   // [8192][768]
  // RoPE trig table aliases the ob region (gemm1 reads it BEFORE attn writes ob)
  float2* ttab = (float2*)(ws + 55050240);                  // [2048][32] float2 = 512KB

  k_convert<<<8704, 256, 0, stream>>>(x, wqkv, wout, xb, wqb, wob, ttab);

  dim3 g1(64, 18);  // M/128 x (3D)/128
  k_gemm<0><<<g1, 256, 0, stream>>>(xb, wqb, nullptr, qb, kb, vtb, ttab, 768, 2304);

  k_attn<<<768, 256, 0, stream>>>(qb, kb, vtb, ob);  // XCD-grouped 1-D grid

  dim3 g2(64, 6);  // M/128 x D/128
  k_gemm<1><<<g2, 256, 0, stream>>>(ob, wob, out, nullptr, nullptr, nullptr, nullptr, 768, 768);
}